// Round 1
// baseline (3655.993 us; speedup 1.0000x reference)
//
#include <hip/hip_runtime.h>
#include <math.h>

#define NYg 1024
#define NXg 1024
#define NSTEPS 64

constexpr float DXf   = 50.0f;
constexpr float DYf   = 50.0f;
constexpr float TTOTf = 32.0f;
constexpr float DTMAXf= 0.5f;
constexpr float EPSf  = 1e-10f;
constexpr float TFREQ = 5.0f;
constexpr float LAPSE = 0.0065f;
constexpr float MELTF = 0.5f;
// FD * (RHO*G)^3 folded in double then cast, like JAX constant folding
constexpr double RHOG = 910.0 * 9.81;
constexpr float  CDf  = (float)(1e-17 * RHOG * RHOG * RHOG);

// ---------------- init: H=0, Za=Zb=Z_topo, smb from Z_topo, scalars ----------------
__global__ __launch_bounds__(256) void k_init(
    const float* __restrict__ precip, const float* __restrict__ tma,
    const float* __restrict__ tmj, const float* __restrict__ ztopo,
    const float* __restrict__ mask,
    float* __restrict__ H, float* __restrict__ Za, float* __restrict__ Zb,
    float* __restrict__ smb, unsigned int* __restrict__ maxD,
    float* __restrict__ time_arr, float* __restrict__ tlast_arr)
{
    int idx = blockIdx.x * blockDim.x + threadIdx.x;
    float TMA = tma[0], TMJ = tmj[0];
    for (int i = idx; i < NYg * NXg; i += gridDim.x * blockDim.x) {
        float z = ztopo[i];
        H[i]  = 0.0f;
        Za[i] = z;
        Zb[i] = z;
        float t_ma = TMA - LAPSE * z;
        float t_mj = TMJ - LAPSE * z;
        float acc  = (t_ma < 0.0f) ? precip[i] : 0.0f;
        float abl  = MELTF * fmaxf(t_mj, 0.0f);
        smb[i] = (acc - abl) * mask[i];
    }
    if (idx < NSTEPS) maxD[idx] = 0u;
    if (idx == 0) { time_arr[0] = 0.0f; tlast_arr[0] = 0.0f; }
}

// ---------------- per step, phase 1: D on staggered grid + global max ----------------
__global__ __launch_bounds__(256) void k_diffus(
    const float* __restrict__ H, const float* __restrict__ Z,
    float* __restrict__ D, unsigned int* __restrict__ maxD_s)
{
    int j = blockIdx.x * blockDim.x + threadIdx.x;   // 0..1023, guard < NX-1
    int i = blockIdx.y;                              // 0..NY-2
    float d = 0.0f;
    if (j < NXg - 1) {
        int base = i * NXg + j;
        float h00 = H[base],       h01 = H[base + 1];
        float h10 = H[base + NXg], h11 = H[base + NXg + 1];
        float z00 = Z[base],       z01 = Z[base + 1];
        float z10 = Z[base + NXg], z11 = Z[base + NXg + 1];
        float havg = 0.25f * (h00 + h11 + h01 + h10);
        float sx = ((z01 - z00) + (z11 - z10)) * (0.5f / DXf);
        float sy = ((z10 - z00) + (z11 - z01)) * (0.5f / DYf);
        float sn = sqrtf(sx * sx + sy * sy + EPSf);
        float h2 = havg * havg;
        float h4 = h2 * h2;
        d = CDf * (h4 * havg) * (sn * sn) + EPSf;
        D[base] = d;   // row stride NXg (last col/row of stride unused)
    }
    // block max-reduce: wave shuffle then LDS across 4 waves
    float m = d;
    #pragma unroll
    for (int off = 32; off >= 1; off >>= 1)
        m = fmaxf(m, __shfl_xor(m, off, 64));
    __shared__ float sm[4];
    int lane = threadIdx.x & 63, wid = threadIdx.x >> 6;
    if (lane == 0) sm[wid] = m;
    __syncthreads();
    if (threadIdx.x == 0) {
        m = fmaxf(fmaxf(sm[0], sm[1]), fmaxf(sm[2], sm[3]));
        atomicMax(maxD_s, __float_as_uint(m));  // all d >= EPS > 0: bit order == float order
    }
}

// ---------------- per step, phase 2: flux divergence, H/Z update, smb refresh ----------------
__global__ __launch_bounds__(256) void k_update(
    float* __restrict__ H, const float* __restrict__ Zin, float* __restrict__ Zout,
    float* __restrict__ smb, const float* __restrict__ D,
    const float* __restrict__ ztopo, const float* __restrict__ precip,
    const float* __restrict__ mask, const float* __restrict__ tma,
    const float* __restrict__ tmj,
    const unsigned int* __restrict__ maxD, float* __restrict__ time_arr,
    float* __restrict__ tlast_arr, int s)
{
    int c = blockIdx.x * blockDim.x + threadIdx.x;   // 0..1023
    int r = blockIdx.y;                              // 0..1023

    float mD = __uint_as_float(maxD[s]);
    float t  = time_arr[s];
    float tl = tlast_arr[s];
    float dt = fminf(2500.0f / (2.7f * mD), DTMAXf);
    if (!(t < TTOTf)) dt = 0.0f;
    float nt  = t + dt;
    bool  upd = (nt - tl) >= TFREQ;

    if (r == 0 && c == 0 && threadIdx.x == 0 && blockIdx.x == 0) {
        time_arr[s + 1]  = nt;
        tlast_arr[s + 1] = upd ? nt : tl;
    }
    if (c >= NXg) return;

    int idx = r * NXg + c;
    float z;
    if (r >= 1 && r <= NYg - 2 && c >= 1 && c <= NXg - 2) {
        float zc = Zin[idx];
        float zl = Zin[idx - 1],  zr = Zin[idx + 1];
        float zt = Zin[idx - NXg], zb = Zin[idx + NXg];
        float d00 = D[(r - 1) * NXg + (c - 1)], d01 = D[(r - 1) * NXg + c];
        float d10 = D[r * NXg + (c - 1)],       d11 = D[r * NXg + c];
        float qxR = -0.5f * (d01 + d11) * (zr - zc) * (1.0f / DXf);
        float qxL = -0.5f * (d00 + d10) * (zc - zl) * (1.0f / DXf);
        float qyB = -0.5f * (d10 + d11) * (zb - zc) * (1.0f / DYf);
        float qyT = -0.5f * (d00 + d01) * (zc - zt) * (1.0f / DYf);
        float dHdt = -((qxR - qxL) * (1.0f / DXf) + (qyB - qyT) * (1.0f / DYf));
        float h = H[idx] + dt * (dHdt + smb[idx]);
        h = fmaxf(h, 0.0f);
        H[idx] = h;
        z = ztopo[idx] + h;
        Zout[idx] = z;
    } else {
        // boundary: H stays 0, Z stays Z_topo (both buffers hold Z_topo from init)
        z = Zin[idx];
    }
    if (upd) {
        float TMA = tma[0], TMJ = tmj[0];
        float t_ma = TMA - LAPSE * z;
        float t_mj = TMJ - LAPSE * z;
        float acc  = (t_ma < 0.0f) ? precip[idx] : 0.0f;
        float abl  = MELTF * fmaxf(t_mj, 0.0f);
        smb[idx] = (acc - abl) * mask[idx];
    }
}

extern "C" void kernel_launch(void* const* d_in, const int* in_sizes, int n_in,
                              void* d_out, int out_size, void* d_ws, size_t ws_size,
                              hipStream_t stream)
{
    const float* precip = (const float*)d_in[0];
    const float* tma    = (const float*)d_in[1];
    const float* tmj    = (const float*)d_in[2];
    const float* ztopo  = (const float*)d_in[3];
    const float* mask   = (const float*)d_in[4];

    float* H = (float*)d_out;                       // H_ice state lives in d_out

    float* Za   = (float*)d_ws;                     // Z_surf buffer A
    float* Zb   = Za + NYg * NXg;                   // Z_surf buffer B
    float* smb  = Zb + NYg * NXg;                   // surface mass balance
    float* Dbuf = smb + NYg * NXg;                  // staggered diffusivity (stride NXg)
    unsigned int* maxD = (unsigned int*)(Dbuf + NYg * NXg);   // per-step max(D) bits
    float* time_arr  = (float*)(maxD + NSTEPS);     // time[s], 65 slots
    float* tlast_arr = time_arr + (NSTEPS + 1);     // t_last[s], 65 slots

    k_init<<<dim3(256), dim3(256), 0, stream>>>(precip, tma, tmj, ztopo, mask,
                                                H, Za, Zb, smb, maxD, time_arr, tlast_arr);

    dim3 blk(256, 1, 1);
    dim3 gD(4, NYg - 1, 1);   // covers 1023 cols x 1023 rows
    dim3 gU(4, NYg, 1);       // full grid

    for (int s = 0; s < NSTEPS; ++s) {
        const float* Zin = (s & 1) ? Zb : Za;
        float*       Zout = (s & 1) ? Za : Zb;
        k_diffus<<<gD, blk, 0, stream>>>(H, Zin, Dbuf, maxD + s);
        k_update<<<gU, blk, 0, stream>>>(H, Zin, Zout, smb, Dbuf, ztopo, precip, mask,
                                         tma, tmj, maxD, time_arr, tlast_arr, s);
    }
}

// Round 2
// 1100.917 us; speedup vs baseline: 3.3209x; 3.3209x over previous
//
#include <hip/hip_runtime.h>
#include <math.h>

#define NYg 1024
#define NXg 1024
#define NSTEPS 64
#define NSLOT 8        // atomic-max slots per step (one per XCD)
#define SLOT_STRIDE 8  // dwords between slots (32 B)

constexpr float DXf   = 50.0f;
constexpr float DYf   = 50.0f;
constexpr float TTOTf = 32.0f;
constexpr float DTMAXf= 0.5f;
constexpr float EPSf  = 1e-10f;
constexpr float TFREQ = 5.0f;
constexpr float LAPSE = 0.0065f;
constexpr float MELTF = 0.5f;
constexpr double RHOG = 910.0 * 9.81;
constexpr float  CDf  = (float)(1e-17 * RHOG * RHOG * RHOG);

// ---------------- init: H=0, Za=Zb=Z_topo, smb from Z_topo, scalars ----------------
__global__ __launch_bounds__(256) void k_init(
    const float* __restrict__ precip, const float* __restrict__ tma,
    const float* __restrict__ tmj, const float* __restrict__ ztopo,
    const float* __restrict__ mask,
    float* __restrict__ H, float* __restrict__ Za, float* __restrict__ Zb,
    float* __restrict__ smb, unsigned int* __restrict__ maxD,
    float* __restrict__ time_arr, float* __restrict__ tlast_arr)
{
    int idx = blockIdx.x * blockDim.x + threadIdx.x;
    float TMA = tma[0], TMJ = tmj[0];
    for (int i = idx; i < NYg * NXg; i += gridDim.x * blockDim.x) {
        float z = ztopo[i];
        H[i]  = 0.0f;
        Za[i] = z;
        Zb[i] = z;
        float t_ma = TMA - LAPSE * z;
        float t_mj = TMJ - LAPSE * z;
        float acc  = (t_ma < 0.0f) ? precip[i] : 0.0f;
        float abl  = MELTF * fmaxf(t_mj, 0.0f);
        smb[i] = (acc - abl) * mask[i];
    }
    // zero all atomic-max slots (NSTEPS * NSLOT * SLOT_STRIDE dwords)
    for (int i = idx; i < NSTEPS * NSLOT * SLOT_STRIDE; i += gridDim.x * blockDim.x)
        maxD[i] = 0u;
    if (idx == 0) { time_arr[0] = 0.0f; tlast_arr[0] = 0.0f; }
}

// ---------------- per step, phase 1: D on staggered grid + spread max ----------------
// 256 blocks; block b -> XCD (b&7) band of 128 rows, 4 contiguous rows per block.
__global__ __launch_bounds__(256) void k_diffus(
    const float* __restrict__ H, const float* __restrict__ Z,
    float* __restrict__ D, unsigned int* __restrict__ maxD_s)
{
    int xcd = blockIdx.x & 7;
    int loc = blockIdx.x >> 3;           // 0..31
    int r0  = xcd * 128 + loc * 4;
    float m = 0.0f;
    #pragma unroll
    for (int k = 0; k < 4; ++k) {
        int i = r0 + k;
        if (i < NYg - 1) {
            const float* Hr = H + i * NXg;
            const float* Zr = Z + i * NXg;
            float*       Dr = D + i * NXg;
            for (int j = threadIdx.x; j < NXg - 1; j += 256) {
                float h00 = Hr[j],       h01 = Hr[j + 1];
                float h10 = Hr[j + NXg], h11 = Hr[j + NXg + 1];
                float z00 = Zr[j],       z01 = Zr[j + 1];
                float z10 = Zr[j + NXg], z11 = Zr[j + NXg + 1];
                float havg = 0.25f * (h00 + h11 + h01 + h10);
                float sx = ((z01 - z00) + (z11 - z10)) * (0.5f / DXf);
                float sy = ((z10 - z00) + (z11 - z01)) * (0.5f / DYf);
                float sn = sqrtf(sx * sx + sy * sy + EPSf);
                float h2 = havg * havg;
                float h4 = h2 * h2;
                float d = CDf * (h4 * havg) * (sn * sn) + EPSf;
                Dr[j] = d;
                m = fmaxf(m, d);
            }
        }
    }
    // block max-reduce: wave shuffle then LDS across 4 waves
    #pragma unroll
    for (int off = 32; off >= 1; off >>= 1)
        m = fmaxf(m, __shfl_xor(m, off, 64));
    __shared__ float sm[4];
    int lane = threadIdx.x & 63, wid = threadIdx.x >> 6;
    if (lane == 0) sm[wid] = m;
    __syncthreads();
    if (threadIdx.x == 0) {
        m = fmaxf(fmaxf(sm[0], sm[1]), fmaxf(sm[2], sm[3]));
        // all d >= EPS > 0: uint bit order == float order; spread over 8 slots
        atomicMax(maxD_s + xcd * SLOT_STRIDE, __float_as_uint(m));
    }
}

// ---------------- per step, phase 2: flux divergence, H/Z update, smb refresh ----------------
__global__ __launch_bounds__(256) void k_update(
    float* __restrict__ H, const float* __restrict__ Zin, float* __restrict__ Zout,
    float* __restrict__ smb, const float* __restrict__ D,
    const float* __restrict__ ztopo, const float* __restrict__ precip,
    const float* __restrict__ mask, const float* __restrict__ tma,
    const float* __restrict__ tmj,
    const unsigned int* __restrict__ maxD, float* __restrict__ time_arr,
    float* __restrict__ tlast_arr, int s)
{
    const unsigned int* slots = maxD + s * NSLOT * SLOT_STRIDE;
    unsigned int mb = slots[0];
    #pragma unroll
    for (int q = 1; q < NSLOT; ++q) mb = max(mb, slots[q * SLOT_STRIDE]);
    float mD = __uint_as_float(mb);
    float t  = time_arr[s];
    float tl = tlast_arr[s];
    float dt = fminf(2500.0f / (2.7f * mD), DTMAXf);
    if (!(t < TTOTf)) dt = 0.0f;
    float nt  = t + dt;
    bool  upd = (nt - tl) >= TFREQ;

    if (blockIdx.x == 0 && threadIdx.x == 0) {
        time_arr[s + 1]  = nt;
        tlast_arr[s + 1] = upd ? nt : tl;
    }

    int xcd = blockIdx.x & 7;
    int loc = blockIdx.x >> 3;
    int r0  = xcd * 128 + loc * 4;
    float TMA = tma[0], TMJ = tmj[0];

    #pragma unroll
    for (int k = 0; k < 4; ++k) {
        int r = r0 + k;
        int rowbase = r * NXg;
        bool interior_row = (r >= 1 && r <= NYg - 2);
        #pragma unroll
        for (int j4 = 0; j4 < 4; ++j4) {
            int c = threadIdx.x + j4 * 256;
            int idx = rowbase + c;
            float z;
            if (interior_row && c >= 1 && c <= NXg - 2) {
                float zc = Zin[idx];
                float zl = Zin[idx - 1],   zr = Zin[idx + 1];
                float zt = Zin[idx - NXg], zb = Zin[idx + NXg];
                float d00 = D[idx - NXg - 1], d01 = D[idx - NXg];
                float d10 = D[idx - 1],       d11 = D[idx];
                float qxR = -0.5f * (d01 + d11) * (zr - zc) * (1.0f / DXf);
                float qxL = -0.5f * (d00 + d10) * (zc - zl) * (1.0f / DXf);
                float qyB = -0.5f * (d10 + d11) * (zb - zc) * (1.0f / DYf);
                float qyT = -0.5f * (d00 + d01) * (zc - zt) * (1.0f / DYf);
                float dHdt = -((qxR - qxL) * (1.0f / DXf) + (qyB - qyT) * (1.0f / DYf));
                float h = H[idx] + dt * (dHdt + smb[idx]);
                h = fmaxf(h, 0.0f);
                H[idx] = h;
                z = ztopo[idx] + h;
                Zout[idx] = z;
            } else {
                z = Zin[idx];   // boundary: H stays 0, Z stays Z_topo
            }
            if (upd) {
                float t_ma = TMA - LAPSE * z;
                float t_mj = TMJ - LAPSE * z;
                float acc  = (t_ma < 0.0f) ? precip[idx] : 0.0f;
                float abl  = MELTF * fmaxf(t_mj, 0.0f);
                smb[idx] = (acc - abl) * mask[idx];
            }
        }
    }
}

extern "C" void kernel_launch(void* const* d_in, const int* in_sizes, int n_in,
                              void* d_out, int out_size, void* d_ws, size_t ws_size,
                              hipStream_t stream)
{
    const float* precip = (const float*)d_in[0];
    const float* tma    = (const float*)d_in[1];
    const float* tmj    = (const float*)d_in[2];
    const float* ztopo  = (const float*)d_in[3];
    const float* mask   = (const float*)d_in[4];

    float* H = (float*)d_out;                       // H_ice state lives in d_out

    // small arrays first, then the 4 MB grids
    unsigned int* maxD = (unsigned int*)d_ws;       // NSTEPS*NSLOT*SLOT_STRIDE dwords
    float* time_arr  = (float*)(maxD + NSTEPS * NSLOT * SLOT_STRIDE);
    float* tlast_arr = time_arr + (NSTEPS + 1);
    float* Za   = (float*)d_ws + 8192;              // 32 KB offset, aligned
    float* Zb   = Za + NYg * NXg;
    float* smb  = Zb + NYg * NXg;
    float* Dbuf = smb + NYg * NXg;

    k_init<<<dim3(256), dim3(256), 0, stream>>>(precip, tma, tmj, ztopo, mask,
                                                H, Za, Zb, smb, maxD, time_arr, tlast_arr);

    dim3 blk(256, 1, 1);
    dim3 grd(256, 1, 1);

    for (int s = 0; s < NSTEPS; ++s) {
        const float* Zin  = (s & 1) ? Zb : Za;
        float*       Zout = (s & 1) ? Za : Zb;
        k_diffus<<<grd, blk, 0, stream>>>(H, Zin, Dbuf, maxD + s * NSLOT * SLOT_STRIDE);
        k_update<<<grd, blk, 0, stream>>>(H, Zin, Zout, smb, Dbuf, ztopo, precip, mask,
                                          tma, tmj, maxD, time_arr, tlast_arr, s);
    }
}